// Round 11
// baseline (87.741 us; speedup 1.0000x reference)
//
#include <hip/hip_runtime.h>
#include <hip/hip_bf16.h>

// Supervised contrastive loss, B=8192, D=256, T=0.07, 100 classes.
//   memset: zero cls_cnt+gacc (one 1032B hipMemsetAsync)
//   prep:   z f32 -> bf16 in FRAGMENT-MAJOR layout zbf2 (1KB per (16-col-tile,
//           kf) MFMA fragment unit, lane-slot = lk*16+l15) + class bucketing.
//   passA:  row sums of exp(z@z^T/T), diag masked. NO LDS, NO barriers:
//           512 blocks = 128 row-tiles(64) x 4 col-quarters, 8 waves each.
//           Per wave: a[4][8] regs (whole 64-row tile, zero B duplication),
//           16 col-tiles streamed with reg-double-buffered b[8] loads --
//           every fragment load is one coalesced global_load_dwordx4 from
//           the L2-resident zbf2. Bound: L2 BW (512MB ~ 15us).
//   passB:  per class (100 blocks x 8 waves): gather members from f32 z
//           (convert with same f2bf -> bitwise-equal fragments), all-pairs
//           MFMA -> sum_same, caching e=exp(d/T) as bf16 in LDS dmat;
//           pass2 reads dmat (no second MFMA pass); atomics into gacc.
//   final:  out = gacc[0]/max(gacc[1],1)

#define BN 8192
#define DD 256
#define INV_T (1.0f / 0.07f)
#define CAPI 256
#define CAP 160
#define IPAD 164

typedef __attribute__((ext_vector_type(8))) __bf16 bf16x8;
typedef __attribute__((ext_vector_type(4))) float f32x4;

static __device__ __forceinline__ unsigned short f2bf(float f) {
    unsigned int u = __builtin_bit_cast(unsigned int, f);
    u = (u + 0x7FFFu + ((u >> 16) & 1u)) >> 16;   // RNE, inputs finite
    return (unsigned short)u;
}
static __device__ __forceinline__ float bf2f(unsigned short s) {
    unsigned int u = (unsigned int)s << 16;
    return __builtin_bit_cast(float, u);
}

// ------- kernel 1: f32 -> bf16 fragment-major zbf2 + class bucketing ------
__global__ __launch_bounds__(256) void k_prep(const float* __restrict__ z,
                                              unsigned short* __restrict__ zbf2,
                                              const int* __restrict__ labels,
                                              int* __restrict__ cls_cnt,
                                              int* __restrict__ cls_idx) {
    const int gid = blockIdx.x * 256 + threadIdx.x;       // 262144 threads
    const float4* z4 = (const float4*)z;
    float4 v0 = z4[gid * 2 + 0];
    float4 v1 = z4[gid * 2 + 1];
    unsigned short r[8];
    r[0] = f2bf(v0.x); r[1] = f2bf(v0.y); r[2] = f2bf(v0.z); r[3] = f2bf(v0.w);
    r[4] = f2bf(v1.x); r[5] = f2bf(v1.y); r[6] = f2bf(v1.z); r[7] = f2bf(v1.w);
    // row j, 16B chunk c5 (k elems [c5*8,+8)) -> frag unit (j>>4)*8 + (c5>>2),
    // lane slot (c5&3)*16 + (j&15)
    const int j = gid >> 5, c5 = gid & 31;
    const int idx16 = (((j >> 4) * 8 + (c5 >> 2)) * 64) + (c5 & 3) * 16 + (j & 15);
    ((uint4*)zbf2)[idx16] = *(const uint4*)r;
    if (gid < BN) {                                       // cls_cnt pre-zeroed
        const int c = labels[gid];
        const int slot = atomicAdd(&cls_cnt[c], 1);
        if (slot < CAPI) cls_idx[c * CAPI + slot] = gid;
    }
}

// ---------------- kernel 2: row sums of exp(z z^T / T), diag masked -------
// Grid 512 = 128 row-tiles(64 rows) x 4 col-quarters. 512 thr = 8 waves.
// Wave w streams col tiles [cq*128 + w*16, +16). No LDS staging, no barriers.
__global__ __launch_bounds__(512, 2) void k_passA(const char* __restrict__ zb2,
                                                  float* __restrict__ sn_part) {
    __shared__ float sn_lds[64];
    const int tid = threadIdx.x;
    const int w = tid >> 6, lane = tid & 63;
    const int l15 = lane & 15, lk = lane >> 4;
    const int rowbase = (blockIdx.x >> 2) * 64;
    const int cq = blockIdx.x & 3;
    const int jt0 = cq * 128 + w * 16;        // first global 16-col tile idx

    if (tid < 64) sn_lds[tid] = 0.f;
    __syncthreads();

    // A fragments: whole 64-row tile, full K, from fragment-major layout.
    const int rt0 = rowbase >> 4;
    bf16x8 a[4][8];
#pragma unroll
    for (int m = 0; m < 4; ++m) {
        const char* p = zb2 + ((size_t)(rt0 + m) * 8192) + lane * 16;
#pragma unroll
        for (int kf = 0; kf < 8; ++kf)
            a[m][kf] = *(const bf16x8*)(p + kf * 1024);
    }

    float snp[4][4] = {};
    bf16x8 b0[8], b1[8];

    auto loadB = [&](bf16x8 (&dst)[8], int jt) {
        const char* p = zb2 + ((size_t)jt * 8192) + lane * 16;
#pragma unroll
        for (int kf = 0; kf < 8; ++kf)
            dst[kf] = *(const bf16x8*)(p + kf * 1024);
    };
    auto computeTile = [&](bf16x8 (&bx)[8], int jt) {
        f32x4 acc[4] = {};
        __builtin_amdgcn_s_setprio(1);
#pragma unroll
        for (int kf = 0; kf < 8; ++kf)
#pragma unroll
            for (int m = 0; m < 4; ++m)
                acc[m] = __builtin_amdgcn_mfma_f32_16x16x32_bf16(a[m][kf], bx[kf], acc[m], 0, 0, 0);
        __builtin_amdgcn_s_setprio(0);
        const int jj = jt * 16 + l15;
#pragma unroll
        for (int m = 0; m < 4; ++m) {
            const int ig = rowbase + m * 16 + lk * 4;
#pragma unroll
            for (int rr = 0; rr < 4; ++rr) {
                float e = __expf(acc[m][rr] * INV_T);
                if (ig + rr == jj) e = 0.f;               // mask diagonal
                snp[m][rr] += e;
            }
        }
    };

    loadB(b0, jt0);
    for (int t = 0; t < 16; t += 2) {
        loadB(b1, jt0 + t + 1);
        computeTile(b0, jt0 + t);
        if (t + 2 < 16) loadB(b0, jt0 + t + 2);
        computeTile(b1, jt0 + t + 1);
    }

    // reduce across the 16 l15 lanes sharing each row, combine waves in LDS
#pragma unroll
    for (int m = 0; m < 4; ++m) {
#pragma unroll
        for (int rr = 0; rr < 4; ++rr) {
            float v = snp[m][rr];
            v += __shfl_xor(v, 1, 64);
            v += __shfl_xor(v, 2, 64);
            v += __shfl_xor(v, 4, 64);
            v += __shfl_xor(v, 8, 64);
            if (l15 == 0)
                atomicAdd(&sn_lds[m * 16 + lk * 4 + rr], v);
        }
    }
    __syncthreads();
    if (tid < 64)
        sn_part[(size_t)cq * BN + rowbase + tid] = sn_lds[tid];
}

// ---------------- kernel 3: per-class positive pairs ----------------------
// 100 blocks x 512 thr (8 waves). Gather from f32 z (same f2bf bits), one
// MFMA pass caching e as bf16 in dmat; pass2 reads dmat only. Atomics into
// gacc[0] (sum row_loss) and gacc[1] (n_valid).
__global__ __launch_bounds__(512) void k_passB(const float* __restrict__ zf,
                                               const float* __restrict__ sn_part,
                                               const int* __restrict__ cls_cnt,
                                               const int* __restrict__ cls_idx,
                                               float* __restrict__ gacc) {
    __shared__ char Zc[CAP * 512];             // swizzled [row][512 B]
    __shared__ unsigned short dmat[CAP * IPAD];// col-major e cache [j][iPad]
    __shared__ int glist[CAP];
    __shared__ float snl[CAP];
    __shared__ float sums[CAP];
    __shared__ float blkL;

    const int c = blockIdx.x;
    const int tid = threadIdx.x;
    const int w = tid >> 6, lane = tid & 63;
    const int l15 = lane & 15, lk = lane >> 4;

    const int n_c = min(cls_cnt[c], CAP);
    const int nt = (n_c + 15) >> 4;
    const int rows_p = nt * 16;

    if (tid < CAP) glist[tid] = (tid < n_c) ? cls_idx[c * CAPI + tid] : 0;
    if (tid == 0) blkL = 0.f;
    __syncthreads();

    // gather: 32 lanes per row; read f32, convert (bitwise == zbf2), write
    // swizzled LDS.
    for (int e2 = w * 2; e2 < rows_p; e2 += 16) {
        const int row = e2 + (lane >> 5);
        const int li = lane & 31;
        const float* src = zf + (size_t)glist[row] * DD + li * 8;
        float4 v0 = *(const float4*)(src);
        float4 v1 = *(const float4*)(src + 4);
        unsigned short r[8];
        r[0] = f2bf(v0.x); r[1] = f2bf(v0.y); r[2] = f2bf(v0.z); r[3] = f2bf(v0.w);
        r[4] = f2bf(v1.x); r[5] = f2bf(v1.y); r[6] = f2bf(v1.z); r[7] = f2bf(v1.w);
        *(uint4*)(Zc + row * 512 + ((li * 16) ^ ((row & 7) << 4))) = *(const uint4*)r;
    }
    __syncthreads();

    // ---- pass 1: sum_same + e-cache ----
    for (int mi = w; mi < nt; mi += 8) {
        const int rowA = mi * 16 + l15;
        const int swa = (rowA & 7) << 4;
        bf16x8 a[8];
#pragma unroll
        for (int kf = 0; kf < 8; ++kf)
            a[kf] = *(const bf16x8*)(Zc + rowA * 512 + ((lk * 16 + kf * 64) ^ swa));
        float sp[4] = {};
        for (int nj = 0; nj < nt; ++nj) {
            const int colB = nj * 16 + l15;
            const int swb = (colB & 7) << 4;
            bf16x8 b[8];
#pragma unroll
            for (int kf = 0; kf < 8; ++kf)
                b[kf] = *(const bf16x8*)(Zc + colB * 512 + ((lk * 16 + kf * 64) ^ swb));
            f32x4 acc = {};
#pragma unroll
            for (int kf = 0; kf < 8; ++kf)
                acc = __builtin_amdgcn_mfma_f32_16x16x32_bf16(a[kf], b[kf], acc, 0, 0, 0);
            unsigned short ep[4];
#pragma unroll
            for (int rr = 0; rr < 4; ++rr) {
                const int i = mi * 16 + lk * 4 + rr;
                const float e = __expf(acc[rr] * INV_T);
                ep[rr] = f2bf(e);
                sp[rr] += (colB < n_c && i != colB) ? e : 0.f;
            }
            uint2 uv;
            uv.x = (unsigned)ep[0] | ((unsigned)ep[1] << 16);
            uv.y = (unsigned)ep[2] | ((unsigned)ep[3] << 16);
            *(uint2*)&dmat[colB * IPAD + mi * 16 + lk * 4] = uv;
        }
#pragma unroll
        for (int rr = 0; rr < 4; ++rr) {
            float v = sp[rr];
            v += __shfl_xor(v, 1, 64);
            v += __shfl_xor(v, 2, 64);
            v += __shfl_xor(v, 4, 64);
            v += __shfl_xor(v, 8, 64);
            if (l15 == 0) sums[mi * 16 + lk * 4 + rr] = v;
        }
    }
    __syncthreads();
    if (tid < CAP)
        snl[tid] = (tid < n_c)
            ? (sn_part[glist[tid]] + sn_part[BN + glist[tid]]
               + sn_part[2 * BN + glist[tid]] + sn_part[3 * BN + glist[tid]]
               - sums[tid])
            : 0.f;
    __syncthreads();

    // ---- pass 2: pair losses from the e-cache (no MFMA) ----
    for (int mi = w; mi < nt; mi += 8) {
        float sneg[4];
#pragma unroll
        for (int rr = 0; rr < 4; ++rr) {
            const int i = mi * 16 + lk * 4 + rr;
            sneg[rr] = (i < n_c) ? snl[i] : 0.f;
        }
        float sp[4] = {};
        for (int nj = 0; nj < nt; ++nj) {
            const int colB = nj * 16 + l15;
            const uint2 pk = *(const uint2*)&dmat[colB * IPAD + mi * 16 + lk * 4];
            float ev[4];
            ev[0] = bf2f((unsigned short)(pk.x & 0xffff));
            ev[1] = bf2f((unsigned short)(pk.x >> 16));
            ev[2] = bf2f((unsigned short)(pk.y & 0xffff));
            ev[3] = bf2f((unsigned short)(pk.y >> 16));
#pragma unroll
            for (int rr = 0; rr < 4; ++rr) {
                const int i = mi * 16 + lk * 4 + rr;
                const float t = log1pf(sneg[rr] / ev[rr]);
                sp[rr] += (colB < n_c && i != colB) ? t : 0.f;
            }
        }
#pragma unroll
        for (int rr = 0; rr < 4; ++rr) {
            float v = sp[rr];
            v += __shfl_xor(v, 1, 64);
            v += __shfl_xor(v, 2, 64);
            v += __shfl_xor(v, 4, 64);
            v += __shfl_xor(v, 8, 64);
            const int i = mi * 16 + lk * 4 + rr;
            if (l15 == 0 && i < n_c && n_c > 1)
                atomicAdd(&blkL, v / (float)(n_c - 1));
        }
    }
    __syncthreads();
    if (tid == 0 && n_c > 1) {
        atomicAdd(&gacc[0], blkL);
        atomicAdd(&gacc[1], (float)n_c);
    }
}

// ---------------- kernel 4: final scalar ----------------------------------
__global__ void k_final(const float* __restrict__ gacc, float* __restrict__ out) {
    if (threadIdx.x == 0) {
        const float L = gacc[0], V = gacc[1];
        out[0] = (V > 0.f) ? L / fmaxf(V, 1.f) : 0.f;
    }
}

extern "C" void kernel_launch(void* const* d_in, const int* in_sizes, int n_in,
                              void* d_out, int out_size, void* d_ws, size_t ws_size,
                              hipStream_t stream) {
    const float* z      = (const float*)d_in[0];
    const int*   labels = (const int*)d_in[1];
    float* out = (float*)d_out;

    char* ws = (char*)d_ws;
    // zbf2 4MB (fragment-major) | sn_part 4xBN f32 | cls_cnt 1KB | gacc 8B |
    // cls_idx 100KB  (total ~4.23MB)
    unsigned short* zbf2 = (unsigned short*)ws;
    size_t off = (size_t)BN * DD * sizeof(unsigned short);
    float* sn_part = (float*)(ws + off);  off += 4 * BN * sizeof(float);
    int*   cls_cnt = (int*)(ws + off);    off += 1024;
    float* gacc    = (float*)(ws + off);  off += 8;
    int*   cls_idx = (int*)(ws + off);    off += 100 * CAPI * sizeof(int);

    hipMemsetAsync(cls_cnt, 0, 1032, stream);   // cls_cnt + gacc (adjacent)
    k_prep  <<<1024, 256, 0, stream>>>(z, zbf2, labels, cls_cnt, cls_idx);
    k_passA <<<512, 512, 0, stream>>>((const char*)zbf2, sn_part);
    k_passB <<<100, 512, 0, stream>>>(z, sn_part, cls_cnt, cls_idx, gacc);
    k_final <<<1, 64, 0, stream>>>(gacc, out);
}